// Round 5
// baseline (3769.487 us; speedup 1.0000x reference)
//
#include <hip/hip_runtime.h>
#include <hip/hip_bf16.h>

// Problem dims
constexpr int NB = 128;   // batch
constexpr int NT = 512;   // seq len
constexpr int NE = 256;   // embed dim
constexpr int NH = 512;   // hidden
constexpr int NV = 64;    // vocab
constexpr int NP = 128;   // output proj dim

// 8 row groups x 8 slice blocks (512 thr: waves 0-3 = layer0, 4-7 = layer1).
// h panels live in global memory in MFMA-fragment layout:
//   panel = 16 rows x 512 cols bf16 = 16 frags; frag kt = 64 lanes x 16B,
//   lane l holds rows l&15, k = kt*32 + (l>>4)*8 .. +7.
constexpr int GROUPS = 8;
constexpr int MR     = 16;
constexpr int NCS    = 64;
constexpr int SLICES = 8;
constexpr int NBLK   = GROUPS * SLICES;   // 64 blocks
constexpr int RING   = 16;                // h0 ring depth
constexpr int FS     = 32;                // flag stride (ints) = 128B

typedef unsigned short u16;
typedef __attribute__((ext_vector_type(8))) short bf16x8v;
typedef __attribute__((ext_vector_type(4))) float f32x4v;

__device__ __forceinline__ u16 f2bf(float x) {
  unsigned u = __builtin_bit_cast(unsigned, x);
  return (u16)((u + 0x7fffu + ((u >> 16) & 1u)) >> 16);  // RNE
}

// ---------------------------------------------------------------------------
__global__ __launch_bounds__(256) void proj_kernel(
    const float* __restrict__ emb, const float* __restrict__ W_xh0,
    const float* __restrict__ b_xh0, float* __restrict__ proj) {
  int v = blockIdx.x >> 1;
  int j = ((blockIdx.x & 1) << 8) + threadIdx.x;
  float acc = b_xh0[j];
  const float* er = emb + v * NE;
  for (int e = 0; e < NE; ++e) acc += er[e] * W_xh0[e * NH + j];
  proj[v * NH + j] = acc;
}

__global__ __launch_bounds__(256) void transpose_bf16_kernel(
    const float* __restrict__ src, u16* __restrict__ dst, int R, int logC) {
  int idx = blockIdx.x * 256 + threadIdx.x;
  int C = 1 << logC;
  if (idx >= R * C) return;
  int r = idx >> logC;
  int c = idx & (C - 1);
  dst[c * R + r] = f2bf(src[idx]);
}

__global__ void zero_flags_kernel(int* flags) {
  flags[blockIdx.x * 256 + threadIdx.x] = 0;   // 4096 ints
}

// ---------------------------------------------------------------------------
__global__ __launch_bounds__(512, 1) void rnn_persist(
    const int* __restrict__ src, const int* __restrict__ lens,
    const float* __restrict__ proj,
    const u16* __restrict__ Wt_hh0,   // [NH][NH] = W^T, bf16
    const u16* __restrict__ Wt_xh1,
    const u16* __restrict__ Wt_hh1,
    const float* __restrict__ b_xh1,
    u16* __restrict__ h0f,            // [RING][GROUPS] fragment panels (16KB each)
    u16* __restrict__ h1f,            // [NT][GROUPS] fragment panels
    int* __restrict__ flags)          // flag0[64*FS] ++ flag1[64*FS]
{
  __shared__ struct {
    float pj[NV][72];
    int srcv[MR][NT];
    int bar0, bar1;
  } sm;

  const int bid = blockIdx.x;
  const int g = bid & (GROUPS - 1);
  const int slice = bid >> 3;
  const int c0 = slice * NCS;
  const int r0 = g * MR;

  const int tid = threadIdx.x;
  const int lane = tid & 63, wave = tid >> 6;
  const int lq = lane >> 4, lr = lane & 15;
  const bool l1w = (wave >= 4);
  const int n0 = (wave & 3) * 16;

  int* flag0 = flags;
  int* flag1 = flags + 64 * FS;
  const int* f0g = flag0 + g * SLICES * FS;
  const int* f1g = flag1 + g * SLICES * FS;
  int* myf0 = flag0 + (g * SLICES + slice) * FS;
  int* myf1 = flag1 + (g * SLICES + slice) * FS;

  // publish sub-offset (dwords) within this group's panel, for even lanes:
  // global col = c0 + n0 + lr -> frag ktg, slot = koct*16+row, jp = dword pair
  const int ktg = slice * 2 + (n0 >> 5);
  const int koct = ((n0 & 16) + lr) >> 3;
  const int jp = (lr & 7) >> 1;
  const int fragoff = ktg * 256 + (koct * 16 + lq * 4) * 4 + jp;

  int ln[4];
#pragma unroll
  for (int i = 0; i < 4; ++i) ln[i] = lens[r0 + lq * 4 + i];
  u16 oreg[4] = {0, 0, 0, 0};

  if (tid == 0) { sm.bar0 = 0; sm.bar1 = 0; }
  if (!l1w) {
#pragma unroll
    for (int it = 0; it < 4; ++it) {       // pj: 64 x 64 f32
      int c = it * 256 + tid;
      int v = c >> 4, j4 = (c & 15) * 4;
      *(float4*)&sm.pj[v][j4] = *(const float4*)&proj[v * NH + c0 + j4];
    }
#pragma unroll
    for (int it = 0; it < 8; ++it)         // src rows: 16 x 512 int
      ((int4*)sm.srcv)[it * 256 + tid] =
          ((const int4*)(src + (size_t)r0 * NT))[it * 256 + tid];
  }
  __syncthreads();   // the only full-block barrier

  // per-wave poll of sibling flags: lanes 0-7 flag0, lanes 8-15 flag1
  auto wait2 = [&](int thr0, int thr1) {
    const int* ap; int thr;
    if (lane < 8)       { ap = f0g + lane * FS;        thr = thr0; }
    else if (lane < 16) { ap = f1g + (lane - 8) * FS;  thr = thr1; }
    else                { ap = f0g;                    thr = (int)0x80000000; }
    for (;;) {
      int v = __hip_atomic_load(ap, __ATOMIC_RELAXED, __HIP_MEMORY_SCOPE_AGENT);
      if (__all(v >= thr)) break;
    }
  };

  if (!l1w) {
    // =============================== layer 0 ===============================
    bf16x8v w0[16];
    {
      const u16* wp = Wt_hh0 + (size_t)(c0 + n0 + lr) * NH + lq * 8;
#pragma unroll
      for (int kt = 0; kt < 16; ++kt) w0[kt] = *(const bf16x8v*)(wp + kt * 32);
    }
    for (int s = 0; s < NT; ++s) {
      f32x4v acc = {0.f, 0.f, 0.f, 0.f};
      if (s > 0) {
        wait2(s, s - 14);                  // flag1 >= s-14: ring WAR guard
        __builtin_amdgcn_fence(__ATOMIC_ACQUIRE, "agent");
        const u16* ap = h0f + ((size_t)((s - 1) & (RING - 1)) * GROUPS + g) * 8192;
        bf16x8v af[16];
#pragma unroll
        for (int kt = 0; kt < 16; ++kt)
          af[kt] = *(const bf16x8v*)(ap + kt * 512 + lane * 8);
#pragma unroll
        for (int kt = 0; kt < 16; ++kt)
          acc = __builtin_amdgcn_mfma_f32_16x16x32_bf16(af[kt], w0[kt], acc, 0, 0, 0);
      }
#pragma unroll
      for (int i = 0; i < 4; ++i) {
        int row = lq * 4 + i;
        float pre = acc[i] + sm.pj[sm.srcv[row][s]][n0 + lr];
        oreg[i] = (s < ln[i]) ? f2bf(tanhf(pre)) : oreg[i];
      }
      unsigned dws[4];
#pragma unroll
      for (int i = 0; i < 4; ++i) {
        int nb = __shfl_xor((int)oreg[i], 1);
        dws[i] = (unsigned)oreg[i] | ((unsigned)nb << 16);
      }
      if (!(lane & 1)) {
        unsigned* dst = (unsigned*)h0f +
            ((size_t)(s & (RING - 1)) * GROUPS + g) * 4096 + fragoff;
#pragma unroll
        for (int i = 0; i < 4; ++i)
          __hip_atomic_store(dst + i * 4, dws[i], __ATOMIC_RELAXED,
                             __HIP_MEMORY_SCOPE_AGENT);
      }
      asm volatile("s_waitcnt vmcnt(0)" ::: "memory");
      if (lane == 0)
        __hip_atomic_fetch_add(&sm.bar0, 1, __ATOMIC_RELEASE,
                               __HIP_MEMORY_SCOPE_WORKGROUP);
      if (wave == 0) {
        while (__hip_atomic_load(&sm.bar0, __ATOMIC_ACQUIRE,
                                 __HIP_MEMORY_SCOPE_WORKGROUP) < 4 * (s + 1)) {}
        if (lane == 0)
          __hip_atomic_store(myf0, s + 1, __ATOMIC_RELAXED,
                             __HIP_MEMORY_SCOPE_AGENT);
      }
    }
  } else {
    // =============================== layer 1 ===============================
    bf16x8v wx[16], wh[16];
    {
      const u16* wpx = Wt_xh1 + (size_t)(c0 + n0 + lr) * NH + lq * 8;
      const u16* wph = Wt_hh1 + (size_t)(c0 + n0 + lr) * NH + lq * 8;
#pragma unroll
      for (int kt = 0; kt < 16; ++kt) {
        wx[kt] = *(const bf16x8v*)(wpx + kt * 32);
        wh[kt] = *(const bf16x8v*)(wph + kt * 32);
      }
    }
    const float bcol = b_xh1[c0 + n0 + lr];

    for (int s = 1; s <= NT; ++s) {
      const int t = s - 1;
      wait2(s, (s >= 2) ? s : (int)0x80000000);
      __builtin_amdgcn_fence(__ATOMIC_ACQUIRE, "agent");
      const u16* ap0 = h0f + ((size_t)((s - 1) & (RING - 1)) * GROUPS + g) * 8192;
      const u16* ap1 = h1f + ((size_t)(t - 1) * GROUPS + g) * 8192;   // valid s>=2
      bf16x8v a0f[16], a1a[8], a1b[8];
#pragma unroll
      for (int kt = 0; kt < 16; ++kt)
        a0f[kt] = *(const bf16x8v*)(ap0 + kt * 512 + lane * 8);
      if (s >= 2) {
#pragma unroll
        for (int kt = 0; kt < 8; ++kt)
          a1a[kt] = *(const bf16x8v*)(ap1 + kt * 512 + lane * 8);
      }
      f32x4v acc = {0.f, 0.f, 0.f, 0.f};
#pragma unroll
      for (int kt = 0; kt < 16; ++kt)
        acc = __builtin_amdgcn_mfma_f32_16x16x32_bf16(a0f[kt], wx[kt], acc, 0, 0, 0);
      if (s >= 2) {
#pragma unroll
        for (int kt = 0; kt < 8; ++kt)
          a1b[kt] = *(const bf16x8v*)(ap1 + (kt + 8) * 512 + lane * 8);
#pragma unroll
        for (int kt = 0; kt < 8; ++kt)
          acc = __builtin_amdgcn_mfma_f32_16x16x32_bf16(a1a[kt], wh[kt], acc, 0, 0, 0);
#pragma unroll
        for (int kt = 0; kt < 8; ++kt)
          acc = __builtin_amdgcn_mfma_f32_16x16x32_bf16(a1b[kt], wh[kt + 8], acc, 0, 0, 0);
      }
#pragma unroll
      for (int i = 0; i < 4; ++i) {
        float pre = acc[i] + bcol;
        oreg[i] = (t < ln[i]) ? f2bf(tanhf(pre)) : oreg[i];
      }
      unsigned dws[4];
#pragma unroll
      for (int i = 0; i < 4; ++i) {
        int nb = __shfl_xor((int)oreg[i], 1);
        dws[i] = (unsigned)oreg[i] | ((unsigned)nb << 16);
      }
      if (!(lane & 1)) {
        unsigned* dst = (unsigned*)h1f + ((size_t)t * GROUPS + g) * 4096 + fragoff;
#pragma unroll
        for (int i = 0; i < 4; ++i)
          __hip_atomic_store(dst + i * 4, dws[i], __ATOMIC_RELAXED,
                             __HIP_MEMORY_SCOPE_AGENT);
      }
      asm volatile("s_waitcnt vmcnt(0)" ::: "memory");
      if (lane == 0)
        __hip_atomic_fetch_add(&sm.bar1, 1, __ATOMIC_RELEASE,
                               __HIP_MEMORY_SCOPE_WORKGROUP);
      if (wave == 4) {
        while (__hip_atomic_load(&sm.bar1, __ATOMIC_ACQUIRE,
                                 __HIP_MEMORY_SCOPE_WORKGROUP) < 4 * s) {}
        if (lane == 0)
          __hip_atomic_store(myf1, s + 1, __ATOMIC_RELAXED,
                             __HIP_MEMORY_SCOPE_AGENT);
      }
    }
  }
}

// ---------------------------------------------------------------------------
// logits from fragment-layout h1f: block per t; wave w owns panels 2w, 2w+1.
__global__ __launch_bounds__(256) void out_gemm(
    const u16* __restrict__ h1f, const u16* __restrict__ fc_wT,
    const float* __restrict__ fc_b, float* __restrict__ out)
{
  const int t = blockIdx.x;
  const int tid = threadIdx.x, lane = tid & 63, wave = tid >> 6;
  const int lq = lane >> 4, lr = lane & 15;
  const int m0 = wave * 32;
  f32x4v acc[2][8];
#pragma unroll
  for (int a = 0; a < 2; ++a)
#pragma unroll
    for (int b = 0; b < 8; ++b) acc[a][b] = (f32x4v){0.f, 0.f, 0.f, 0.f};

  const u16* p0 = h1f + ((size_t)t * GROUPS + wave * 2) * 8192;
  const u16* p1 = p0 + 8192;
#pragma unroll 2
  for (int kt = 0; kt < 16; ++kt) {
    bf16x8v a0 = *(const bf16x8v*)(p0 + kt * 512 + lane * 8);
    bf16x8v a1 = *(const bf16x8v*)(p1 + kt * 512 + lane * 8);
    int kb = kt * 32 + lq * 8;
#pragma unroll
    for (int ni = 0; ni < 8; ++ni) {
      bf16x8v bb = *(const bf16x8v*)(fc_wT + (size_t)(ni * 16 + lr) * NH + kb);
      acc[0][ni] = __builtin_amdgcn_mfma_f32_16x16x32_bf16(a0, bb, acc[0][ni], 0, 0, 0);
      acc[1][ni] = __builtin_amdgcn_mfma_f32_16x16x32_bf16(a1, bb, acc[1][ni], 0, 0, 0);
    }
  }
#pragma unroll
  for (int mi = 0; mi < 2; ++mi)
#pragma unroll
    for (int ni = 0; ni < 8; ++ni)
#pragma unroll
      for (int i = 0; i < 4; ++i) {
        int b_ = m0 + mi * 16 + lq * 4 + i;
        int p = ni * 16 + lr;
        out[((size_t)b_ * NT + t) * NP + p] = acc[mi][ni][i] + fc_b[p];
      }
}

// ---------------------------------------------------------------------------
extern "C" void kernel_launch(void* const* d_in, const int* in_sizes, int n_in,
                              void* d_out, int out_size, void* d_ws, size_t ws_size,
                              hipStream_t stream) {
  const int*   src   = (const int*)  d_in[0];
  const int*   lens  = (const int*)  d_in[1];
  const float* emb   = (const float*)d_in[2];
  const float* W_xh0 = (const float*)d_in[3];
  const float* b_xh0 = (const float*)d_in[4];
  const float* W_hh0 = (const float*)d_in[5];
  const float* W_xh1 = (const float*)d_in[6];
  const float* b_xh1 = (const float*)d_in[7];
  const float* W_hh1 = (const float*)d_in[8];
  const float* fc_w  = (const float*)d_in[9];
  const float* fc_b  = (const float*)d_in[10];
  float* out = (float*)d_out;

  char* ws = (char*)d_ws;
  auto alloc = [&](size_t bytes) { char* p = ws; ws += (bytes + 255) & ~size_t(255); return p; };
  float* proj   = (float*)alloc(NV * NH * 4);
  u16* Wt_hh0   = (u16*)  alloc(NH * NH * 2);
  u16* Wt_xh1   = (u16*)  alloc(NH * NH * 2);
  u16* Wt_hh1   = (u16*)  alloc(NH * NH * 2);
  u16* fc_wT    = (u16*)  alloc(NP * NH * 2);
  u16* h0f      = (u16*)  alloc((size_t)RING * GROUPS * 8192 * 2);
  u16* h1f      = (u16*)  alloc((size_t)NT * GROUPS * 8192 * 2);
  int* flags    = (int*)  alloc(2 * 64 * FS * 4);

  proj_kernel<<<NV * 2, 256, 0, stream>>>(emb, W_xh0, b_xh0, proj);
  transpose_bf16_kernel<<<(NH * NH + 255) / 256, 256, 0, stream>>>(W_hh0, Wt_hh0, NH, 9);
  transpose_bf16_kernel<<<(NH * NH + 255) / 256, 256, 0, stream>>>(W_xh1, Wt_xh1, NH, 9);
  transpose_bf16_kernel<<<(NH * NH + 255) / 256, 256, 0, stream>>>(W_hh1, Wt_hh1, NH, 9);
  transpose_bf16_kernel<<<(NH * NP + 255) / 256, 256, 0, stream>>>(fc_w, fc_wT, NH, 7);
  zero_flags_kernel<<<16, 256, 0, stream>>>(flags);

  {
    void* kargs[] = { (void*)&src, (void*)&lens, (void*)&proj, (void*)&Wt_hh0,
                      (void*)&Wt_xh1, (void*)&Wt_hh1, (void*)&b_xh1,
                      (void*)&h0f, (void*)&h1f, (void*)&flags };
    hipError_t e = hipLaunchCooperativeKernel((void*)rnn_persist, dim3(NBLK), dim3(512),
                                              kargs, 0, stream);
    if (e != hipSuccess) {
      rnn_persist<<<NBLK, 512, 0, stream>>>(src, lens, proj, Wt_hh0, Wt_xh1,
                                            Wt_hh1, b_xh1, h0f, h1f, flags);
    }
  }

  out_gemm<<<NT, 256, 0, stream>>>(h1f, fc_wT, fc_b, out);
}

// Round 9
// 1531.035 us; speedup vs baseline: 2.4621x; 2.4621x over previous
//
#include <hip/hip_runtime.h>
#include <hip/hip_bf16.h>

// Problem dims
constexpr int NB = 128;   // batch
constexpr int NT = 512;   // seq len
constexpr int NE = 256;   // embed dim
constexpr int NH = 512;   // hidden
constexpr int NV = 64;    // vocab
constexpr int NP = 128;   // output proj dim

// 8 row groups x 8 slice blocks (512 thr: waves 0-3 layer0, 4-7 layer1).
// Transport (r4-proven, streamlined): h exchange through IC via sc1 (agent)
// ops only. Publishes are 16B sc1 stores; panel loads are 16B sc1 loads
// (bypass stale L0/L2 -> no per-stage acquire fence needed). Flags: agent
// relaxed atomics, one poller set (tid<8) per block.
constexpr int GROUPS = 8;
constexpr int MR     = 16;
constexpr int NCS    = 64;
constexpr int SLICES = 8;
constexpr int NBLK   = GROUPS * SLICES;   // 64 blocks
constexpr int RING   = 16;                // h0 ring depth
constexpr int FS     = 32;                // flag stride (ints) = 128B line

typedef unsigned short u16;
typedef __attribute__((ext_vector_type(8))) short bf16x8v;
typedef __attribute__((ext_vector_type(4))) float f32x4v;
typedef __attribute__((ext_vector_type(4))) unsigned u32x4;   // asm-safe 16B

__device__ __forceinline__ u16 f2bf(float x) {
  unsigned u = __builtin_bit_cast(unsigned, x);
  return (u16)((u + 0x7fffu + ((u >> 16) & 1u)) >> 16);  // RNE
}

// sc1 = agent-scope cache behavior (the bits LLVM emits for agent atomics):
// loads read past L0/L2 (IC), stores write through to IC.
__device__ __forceinline__ void ld2_sc1_x4(const void* p0, const void* p1,
                                           u32x4& a, u32x4& b) {
  asm volatile("global_load_dwordx4 %0, %2, off sc1\n\t"
               "global_load_dwordx4 %1, %3, off sc1\n\t"
               "s_waitcnt vmcnt(0)"
               : "=&v"(a), "=&v"(b) : "v"(p0), "v"(p1) : "memory");
}
__device__ __forceinline__ void st_sc1_x4(void* p, u32x4 v) {
  asm volatile("global_store_dwordx4 %0, %1, off sc1" :: "v"(p), "v"(v) : "memory");
}

// ---------------------------------------------------------------------------
__global__ __launch_bounds__(256) void proj_kernel(
    const float* __restrict__ emb, const float* __restrict__ W_xh0,
    const float* __restrict__ b_xh0, float* __restrict__ proj) {
  int v = blockIdx.x >> 1;
  int j = ((blockIdx.x & 1) << 8) + threadIdx.x;
  float acc = b_xh0[j];
  const float* er = emb + v * NE;
  for (int e = 0; e < NE; ++e) acc += er[e] * W_xh0[e * NH + j];
  proj[v * NH + j] = acc;
}

__global__ __launch_bounds__(256) void transpose_bf16_kernel(
    const float* __restrict__ src, u16* __restrict__ dst, int R, int logC) {
  int idx = blockIdx.x * 256 + threadIdx.x;
  int C = 1 << logC;
  if (idx >= R * C) return;
  int r = idx >> logC;
  int c = idx & (C - 1);
  dst[c * R + r] = f2bf(src[idx]);
}

__global__ void zero_flags_kernel(int* flags) {
  int i = blockIdx.x * 256 + threadIdx.x;
  if (i < NBLK * FS) flags[i] = 0;
}

// ---------------------------------------------------------------------------
// Stage a 16x512 bf16 panel (row stride NH) into fragment-major swizzled LDS.
// frag kt holds 64 lanes x 16B; slot = ((koct<<4)|row) ^ kt (conflict-free).
__device__ __forceinline__ void stage_panel(const u16* __restrict__ gsrc,
                                            u16* __restrict__ buf, int tid) {
  int idx0 = tid, idx1 = 512 + tid;
  int row0 = idx0 >> 6, k80 = idx0 & 63;
  int row1 = idx1 >> 6, k81 = idx1 & 63;
  u32x4 a, b;
  ld2_sc1_x4(gsrc + row0 * NH + k80 * 8, gsrc + row1 * NH + k81 * 8, a, b);
  int kt0 = k80 >> 2, s0 = (((k80 & 3) << 4) | row0) ^ kt0;
  int kt1 = k81 >> 2, s1 = (((k81 & 3) << 4) | row1) ^ kt1;
  *(u32x4*)(buf + (kt0 << 9) + (s0 << 3)) = a;
  *(u32x4*)(buf + (kt1 << 9) + (s1 << 3)) = b;
}

__device__ __forceinline__ bf16x8v frag_A(const u16* __restrict__ buf,
                                          int kt, int lane) {
  return *(const bf16x8v*)(buf + (kt << 9) + (((lane ^ kt) & 63) << 3));
}

// ---------------------------------------------------------------------------
__global__ __launch_bounds__(512, 1) void rnn_persist(
    const int* __restrict__ src, const int* __restrict__ lens,
    const float* __restrict__ proj,
    const u16* __restrict__ Wt_hh0,   // [NH][NH] = W^T, bf16
    const u16* __restrict__ Wt_xh1,
    const u16* __restrict__ Wt_hh1,
    const float* __restrict__ b_xh1,
    u16* __restrict__ h0_ring,        // [RING][NB][NH]
    u16* __restrict__ h1_all,         // [NT][NB][NH]
    int* __restrict__ flags)          // [NBLK][FS]
{
  __shared__ struct {
    u16 a0[16 * 512];    // h0(s-1) panel
    u16 a1[16 * 512];    // h1(s-2) panel
    float pj[NV][72];
    int srcv[MR][NT];
    u16 rep0[16][72];
    u16 rep1[16][72];
  } sm;

  const int bid = blockIdx.x;
  const int g = bid & (GROUPS - 1);
  const int slice = bid >> 3;
  const int c0 = slice * NCS;
  const int r0 = g * MR;

  const int tid = threadIdx.x;
  const int lane = tid & 63, wave = tid >> 6;
  const int lq = lane >> 4, lr = lane & 15;
  const bool l1w = (wave >= 4);
  const int n0 = (wave & 3) * 16;
  const size_t HS = (size_t)NB * NH;

  int* myflag = flags + bid * FS;

  // ---- one-time: weights -> VGPRs, pj + src -> LDS ----
  bf16x8v w0[16], wx[16], wh[16];
  if (!l1w) {
    const u16* wp = Wt_hh0 + (size_t)(c0 + n0 + lr) * NH + lq * 8;
#pragma unroll
    for (int kt = 0; kt < 16; ++kt) w0[kt] = *(const bf16x8v*)(wp + kt * 32);
  } else {
    const u16* wpx = Wt_xh1 + (size_t)(c0 + n0 + lr) * NH + lq * 8;
    const u16* wph = Wt_hh1 + (size_t)(c0 + n0 + lr) * NH + lq * 8;
#pragma unroll
    for (int kt = 0; kt < 16; ++kt) {
      wx[kt] = *(const bf16x8v*)(wpx + kt * 32);
      wh[kt] = *(const bf16x8v*)(wph + kt * 32);
    }
  }
  const float bcol = l1w ? b_xh1[c0 + n0 + lr] : 0.f;

#pragma unroll
  for (int it = 0; it < 2; ++it) {         // pj: 64 x 64 f32
    int c = it * 512 + tid;
    int v = c >> 4, j4 = (c & 15) * 4;
    *(float4*)&sm.pj[v][j4] = *(const float4*)&proj[v * NH + c0 + j4];
  }
#pragma unroll
  for (int it = 0; it < 4; ++it)           // src rows: 16 x 512 int
    ((int4*)sm.srcv)[it * 512 + tid] =
        ((const int4*)(src + (size_t)r0 * NT))[it * 512 + tid];

  int ln[4];
#pragma unroll
  for (int i = 0; i < 4; ++i) ln[i] = lens[r0 + lq * 4 + i];
  u16 oreg[4] = {0, 0, 0, 0};
  __syncthreads();

  // ================================ main loop ==============================
  for (int s = 0; s <= NT; ++s) {
    if (s > 0) {
      // wait: all 8 group sibs published stage s-1 (covers ring WAR, depth 16)
      if (tid < 8) {
        const int* fp = flags + (((tid * 8) | g)) * FS;
        while (__hip_atomic_load(fp, __ATOMIC_RELAXED,
                                 __HIP_MEMORY_SCOPE_AGENT) < s) {}
      }
      __syncthreads();
      stage_panel(h0_ring + (size_t)((s - 1) & (RING - 1)) * HS + (size_t)r0 * NH,
                  sm.a0, tid);
      if (s >= 2)
        stage_panel(h1_all + (size_t)(s - 2) * HS + (size_t)r0 * NH, sm.a1, tid);
      __syncthreads();
    }

    if (!l1w) {
      // ---------------- layer 0: h0(s) ----------------
      if (s < NT) {
        f32x4v acc = {0.f, 0.f, 0.f, 0.f};
        if (s > 0) {
#pragma unroll
          for (int kt = 0; kt < 16; ++kt)
            acc = __builtin_amdgcn_mfma_f32_16x16x32_bf16(
                frag_A(sm.a0, kt, lane), w0[kt], acc, 0, 0, 0);
        }
#pragma unroll
        for (int i = 0; i < 4; ++i) {
          int row = lq * 4 + i;
          float pre = acc[i] + sm.pj[sm.srcv[row][s]][n0 + lr];
          oreg[i] = (s < ln[i]) ? f2bf(tanhf(pre)) : oreg[i];
          sm.rep0[row][n0 + lr] = oreg[i];
        }
      }
    } else {
      // ---------------- layer 1: h1(s-1) ----------------
      if (s >= 1) {
        const int t = s - 1;
        f32x4v accx = {0.f, 0.f, 0.f, 0.f}, acch = {0.f, 0.f, 0.f, 0.f};
#pragma unroll
        for (int kt = 0; kt < 16; ++kt)
          accx = __builtin_amdgcn_mfma_f32_16x16x32_bf16(
              frag_A(sm.a0, kt, lane), wx[kt], accx, 0, 0, 0);
        if (s >= 2) {
#pragma unroll
          for (int kt = 0; kt < 16; ++kt)
            acch = __builtin_amdgcn_mfma_f32_16x16x32_bf16(
                frag_A(sm.a1, kt, lane), wh[kt], acch, 0, 0, 0);
        }
#pragma unroll
        for (int i = 0; i < 4; ++i) {
          int row = lq * 4 + i;
          float pre = accx[i] + acch[i] + bcol;
          oreg[i] = (t < ln[i]) ? f2bf(tanhf(pre)) : oreg[i];
          sm.rep1[row][n0 + lr] = oreg[i];
        }
      }
    }
    __syncthreads();

    // ---- publish: 256 threads x one 16B sc1 store (write-through to IC) ----
    if (tid < 256) {
      int p = tid >> 7, e = tid & 127;
      int row = e >> 3, q = e & 7;        // 8 x 16B per 64-col row slice
      if (p == 0) {
        if (s < NT)
          st_sc1_x4(h0_ring + (size_t)(s & (RING - 1)) * HS +
                        (size_t)(r0 + row) * NH + c0 + q * 8,
                    *(const u32x4*)&sm.rep0[row][q * 8]);
      } else if (s >= 1) {
        st_sc1_x4(h1_all + (size_t)(s - 1) * HS +
                      (size_t)(r0 + row) * NH + c0 + q * 8,
                  *(const u32x4*)&sm.rep1[row][q * 8]);
      }
    }
    asm volatile("s_waitcnt vmcnt(0)" ::: "memory");
    __syncthreads();
    if (tid == 0)
      __hip_atomic_store(myflag, s + 1, __ATOMIC_RELAXED,
                         __HIP_MEMORY_SCOPE_AGENT);
  }
}

// ---------------------------------------------------------------------------
__global__ __launch_bounds__(256) void out_gemm(
    const u16* __restrict__ h1_all, const u16* __restrict__ fc_wT,
    const float* __restrict__ fc_b, float* __restrict__ out)
{
  const int t = blockIdx.x;
  const int tid = threadIdx.x, lane = tid & 63, wave = tid >> 6;
  const int lq = lane >> 4, lr = lane & 15;
  const int m0 = wave * 32;
  f32x4v acc[2][8];
#pragma unroll
  for (int a = 0; a < 2; ++a)
#pragma unroll
    for (int b = 0; b < 8; ++b) acc[a][b] = (f32x4v){0.f, 0.f, 0.f, 0.f};

  const u16* a0p = h1_all + ((size_t)t * NB + m0 + lr) * NH;
  const u16* a1p = a0p + 16 * NH;
#pragma unroll 2
  for (int kt = 0; kt < 16; ++kt) {
    int kb = kt * 32 + lq * 8;
    bf16x8v a0 = *(const bf16x8v*)(a0p + kb);
    bf16x8v a1 = *(const bf16x8v*)(a1p + kb);
#pragma unroll
    for (int ni = 0; ni < 8; ++ni) {
      bf16x8v bb = *(const bf16x8v*)(fc_wT + (size_t)(ni * 16 + lr) * NH + kb);
      acc[0][ni] = __builtin_amdgcn_mfma_f32_16x16x32_bf16(a0, bb, acc[0][ni], 0, 0, 0);
      acc[1][ni] = __builtin_amdgcn_mfma_f32_16x16x32_bf16(a1, bb, acc[1][ni], 0, 0, 0);
    }
  }
#pragma unroll
  for (int mi = 0; mi < 2; ++mi)
#pragma unroll
    for (int ni = 0; ni < 8; ++ni)
#pragma unroll
      for (int i = 0; i < 4; ++i) {
        int b_ = m0 + mi * 16 + lq * 4 + i;
        int p = ni * 16 + lr;
        out[((size_t)b_ * NT + t) * NP + p] = acc[mi][ni][i] + fc_b[p];
      }
}

// ---------------------------------------------------------------------------
extern "C" void kernel_launch(void* const* d_in, const int* in_sizes, int n_in,
                              void* d_out, int out_size, void* d_ws, size_t ws_size,
                              hipStream_t stream) {
  const int*   src   = (const int*)  d_in[0];
  const int*   lens  = (const int*)  d_in[1];
  const float* emb   = (const float*)d_in[2];
  const float* W_xh0 = (const float*)d_in[3];
  const float* b_xh0 = (const float*)d_in[4];
  const float* W_hh0 = (const float*)d_in[5];
  const float* W_xh1 = (const float*)d_in[6];
  const float* b_xh1 = (const float*)d_in[7];
  const float* W_hh1 = (const float*)d_in[8];
  const float* fc_w  = (const float*)d_in[9];
  const float* fc_b  = (const float*)d_in[10];
  float* out = (float*)d_out;

  char* ws = (char*)d_ws;
  auto alloc = [&](size_t bytes) { char* p = ws; ws += (bytes + 255) & ~size_t(255); return p; };
  float* proj   = (float*)alloc(NV * NH * 4);
  u16* Wt_hh0   = (u16*)  alloc(NH * NH * 2);
  u16* Wt_xh1   = (u16*)  alloc(NH * NH * 2);
  u16* Wt_hh1   = (u16*)  alloc(NH * NH * 2);
  u16* fc_wT    = (u16*)  alloc(NP * NH * 2);
  u16* h0_ring  = (u16*)  alloc((size_t)RING * NB * NH * 2);
  u16* h1_all   = (u16*)  alloc((size_t)NT * NB * NH * 2);
  int* flags    = (int*)  alloc(NBLK * FS * 4);

  proj_kernel<<<NV * 2, 256, 0, stream>>>(emb, W_xh0, b_xh0, proj);
  transpose_bf16_kernel<<<(NH * NH + 255) / 256, 256, 0, stream>>>(W_hh0, Wt_hh0, NH, 9);
  transpose_bf16_kernel<<<(NH * NH + 255) / 256, 256, 0, stream>>>(W_xh1, Wt_xh1, NH, 9);
  transpose_bf16_kernel<<<(NH * NH + 255) / 256, 256, 0, stream>>>(W_hh1, Wt_hh1, NH, 9);
  transpose_bf16_kernel<<<(NH * NP + 255) / 256, 256, 0, stream>>>(fc_w, fc_wT, NH, 7);
  zero_flags_kernel<<<(NBLK * FS + 255) / 256, 256, 0, stream>>>(flags);

  {
    void* kargs[] = { (void*)&src, (void*)&lens, (void*)&proj, (void*)&Wt_hh0,
                      (void*)&Wt_xh1, (void*)&Wt_hh1, (void*)&b_xh1,
                      (void*)&h0_ring, (void*)&h1_all, (void*)&flags };
    hipError_t e = hipLaunchCooperativeKernel((void*)rnn_persist, dim3(NBLK), dim3(512),
                                              kargs, 0, stream);
    if (e != hipSuccess) {
      rnn_persist<<<NBLK, 512, 0, stream>>>(src, lens, proj, Wt_hh0, Wt_xh1,
                                            Wt_hh1, b_xh1, h0_ring, h1_all, flags);
    }
  }

  out_gemm<<<NT, 256, 0, stream>>>(h1_all, fc_wT, fc_b, out);
}